// Round 11
// baseline (233.999 us; speedup 1.0000x reference)
//
#include <hip/hip_runtime.h>
#include <math.h>

#define BN_ 8
#define CIN 256
#define COUT 256
#define HH 64
#define WW 64
#define HW 4096
#define KK 9
#define OC 18
#define EPS 1e-5f
#define NTOT (BN_ * COUT * HW)

// ws layout (float units):
//   wTb:    bf16 [72][4][256][8] shorts = 294912 floats (main GEMM A image)
//   wob:    bf16 [72][4][32][8] shorts  = 36864 floats  (offset-conv A image)
//   stats:  [2][COUT]                   = 512 floats
//   xt:     bf16 [B][32][HW][8] shorts  = 4194304 floats (g8-planar x)
#define WTB_WS 589824
#define WOB_WS 884736
#define ST_WS  921600
#define XT_WS  922112

typedef float f32x4 __attribute__((ext_vector_type(4)));
typedef float f32x2 __attribute__((ext_vector_type(2)));
typedef short s16x8 __attribute__((ext_vector_type(8)));
typedef unsigned int u32x4 __attribute__((ext_vector_type(4)));

__device__ __forceinline__ unsigned short f2bf(float f) {
  unsigned int u = __float_as_uint(f);
  unsigned int r = (u + 0x7fffu + ((u >> 16) & 1u)) >> 16;  // RNE
  return (unsigned short)r;
}
__device__ __forceinline__ float bf2f(short s) {
  return __uint_as_float(((unsigned int)(unsigned short)s) << 16);
}

// ---------------- Kernel T: transpose x -> xt[b][g8][p][8] bf16 ----------------
__global__ __launch_bounds__(256) void xpose_kernel(
    const float* __restrict__ x, unsigned short* __restrict__ xt) {
  __shared__ float s[64][65];
  const int t = threadIdx.x;
  const int p0 = blockIdx.x * 64;
  const int c0 = blockIdx.y * 64;
  const int b  = blockIdx.z;
  const float* xb = x + ((size_t)b * CIN + c0) * HW + p0;
#pragma unroll
  for (int pass = 0; pass < 4; ++pass) {
    int cr = pass * 16 + (t >> 4);
    int ps = (t & 15) * 4;
    float4 v = *(const float4*)(xb + (size_t)cr * HW + ps);
    s[ps + 0][cr] = v.x; s[ps + 1][cr] = v.y; s[ps + 2][cr] = v.z; s[ps + 3][cr] = v.w;
  }
  __syncthreads();
  unsigned short* xo = xt + (size_t)b * 32 * HW * 8;
#pragma unroll
  for (int r = 0; r < 2; ++r) {
    int flat = r * 256 + t;
    int pr = flat >> 3, sub = flat & 7;
    int g8 = (c0 >> 3) + sub;
    s16x8 v;
#pragma unroll
    for (int j = 0; j < 8; ++j) v[j] = (short)f2bf(s[pr][sub * 8 + j]);
    *(s16x8*)(xo + ((size_t)g8 * HW + p0 + pr) * 8) = v;
  }
}

// ---------------- Kernel P: pack w_off + w, zero stats (merged prep) ----------------
__global__ __launch_bounds__(256) void prep_kernel(
    const float* __restrict__ w_off, const float* __restrict__ w,
    unsigned short* __restrict__ wob, unsigned short* __restrict__ wTb,
    float* __restrict__ stats) {
  const int kb = blockIdx.x;          // 0..71
  const int kk = kb >> 3;
  const int c0 = (kb & 7) << 5;
  const int t = threadIdx.x;
  if (kb == 71) { stats[t] = 0.f; stats[256 + t] = 0.f; }
  // w_off pack (M=32 pad)
#pragma unroll
  for (int r = 0; r < 4; ++r) {
    int e = r * 256 + t;              // g*256 + m*8 + j
    int g = e >> 8, m = (e >> 3) & 31, j = e & 7;
    int c = c0 + g * 8 + j;
    unsigned short v = 0;
    if (m < OC) v = f2bf(w_off[((size_t)m * CIN + c) * 9 + kk]);
    wob[(size_t)kb * 1024 + e] = v;
  }
  // w pack (k-major)
#pragma unroll
  for (int g = 0; g < 4; ++g)
#pragma unroll
    for (int j = 0; j < 8; ++j) {
      int c = c0 + g * 8 + j;
      wTb[(((size_t)kb * 4 + g) * 256 + t) * 8 + j] =
          f2bf(w[((size_t)t * CIN + c) * 9 + kk]);
    }
}

// ---------------- Kernel B: fused offset-conv + gather MFMA GEMM, N=128 ----------------
// R10 structure (grid 256, block 1024 = 16 waves, M=16/wave, N=128) with a
// 2-DEEP gather pipeline: body I gathers target I+2 (before MFMA -> a full
// body+MFMA of latency slack) and combines target I+1 (after MFMA, reading
// loads issued one whole body earlier). Hazards: cofs single-buffered (last
// old-group gather is at body 4k+1; calc at 4k+2 precedes the first new-group
// gather); qw staged in qwN, committed after the old-group combine in body
// 4k+2; g buffers indexed by target parity (gather fills I&1, combine drains
// (I+1)&1). Corner addresses kept as pointers incremented +512KB/iter.
__global__ __launch_bounds__(1024, 4) void gemm_kernel(
    const unsigned short* __restrict__ xt, const unsigned short* __restrict__ wTb,
    const unsigned short* __restrict__ wob, const float* __restrict__ b_off,
    const float* __restrict__ bias, float* __restrict__ out,
    float* __restrict__ stats) {
  __shared__ __align__(16) char lds[81920];   // 64KB sb/red (s_b aliases) + 16KB s_off
  const int t = threadIdx.x;
  const int lane = t & 63;
  const int wv = t >> 6;               // 0..15
  const int b = blockIdx.x & 7;
  const int hh2 = blockIdx.x >> 3;     // double-row tile: rows 2*hh2, 2*hh2+1
  const int p0 = hh2 * 128;
  const int col = t & 127;             // gather pixel within 128-px tile
  const int oct = t >> 7;              // channel octet (8ch) within 64-chunk
  const int fr = lane & 15, fq = lane >> 4;
  const unsigned short* xtb = xt + (size_t)b * 32 * HW * 8;
  float* s_off = (float*)(lds + 65536);          // [32][128] f32 (rows 0..17 used)
  unsigned short (*s_b)[8192] = (unsigned short(*)[8192])lds;  // 2 x 16KB, aliases red

  // ================= offset-conv prologue =================
  {
    const int wg = wv & 7;             // ki group: ki = wg*9 + s
    const int half = wv >> 3;          // pixel half == row within tile
    const int yrow = 2 * hh2 + half;
    unsigned short* sb = (unsigned short*)lds + wv * 2048;  // wave-private 4KB
    f32x4 acc_o[2][4] = {};

    auto fetch = [&](int s, s16x8* V, s16x8* AF) {
      const int ki = wg * 9 + s;
      const int kk = ki >> 3, cc0g = (ki & 7) << 2;
      const int ky = kk / 3 - 1, kx = kk % 3 - 1;
      const int y = yrow + ky;
      const int xcol = lane + kx;
      const bool ok = (y >= 0) && (y < HH) && (xcol >= 0) && (xcol < WW);
      const int pix = y * WW + xcol;
#pragma unroll
      for (int g = 0; g < 4; ++g) {
        s16x8 v = {0, 0, 0, 0, 0, 0, 0, 0};
        if (ok)
          __builtin_memcpy(&v, (const char*)xtb + (((size_t)(cc0g + g)) << 16) + (size_t)pix * 16, 16);
        V[g] = v;
      }
      const unsigned short* ap = wob + (size_t)ki * 1024;
#pragma unroll
      for (int i = 0; i < 2; ++i)
        AF[i] = *(const s16x8*)&ap[(fq * 32 + i * 16 + fr) * 8];
    };

    s16x8 VE[4], VO[4], afE2[2], afO2[2];
    fetch(0, VE, afE2);

#define OBODY(S, VC, VN, AFC, AFN)                                             \
    {                                                                          \
      _Pragma("unroll")                                                        \
      for (int g = 0; g < 4; ++g)                                              \
        *(s16x8*)&sb[(g * 64 + lane) * 8] = VC[g];                             \
      if ((S) + 1 < 9) fetch((S) + 1, VN, AFN);                                \
      s16x8 bf[4];                                                             \
      _Pragma("unroll")                                                        \
      for (int jn = 0; jn < 4; ++jn)                                           \
        bf[jn] = *(const s16x8*)&sb[(fq * 64 + jn * 16 + fr) * 8];             \
      _Pragma("unroll")                                                        \
      for (int i = 0; i < 2; ++i)                                              \
        _Pragma("unroll")                                                      \
        for (int jn = 0; jn < 4; ++jn)                                         \
          acc_o[i][jn] = __builtin_amdgcn_mfma_f32_16x16x32_bf16(              \
              AFC[i], bf[jn], acc_o[i][jn], 0, 0, 0);                          \
    }

    for (int sp = 0; sp < 4; ++sp) {
      OBODY(2 * sp, VE, VO, afE2, afO2)
      OBODY(2 * sp + 1, VO, VE, afO2, afE2)
    }
    OBODY(8, VE, VO, afE2, afO2)
#undef OBODY

    __syncthreads();                  // sb dead; red region takes over
    float* red = (float*)lds;
    // two passes: half h's 8 wave-partials (64KB) -> reduce -> s_off cols
#pragma unroll
    for (int pass = 0; pass < 2; ++pass) {
      if (half == pass) {
#pragma unroll
        for (int i = 0; i < 2; ++i)
#pragma unroll
          for (int jn = 0; jn < 4; ++jn)
#pragma unroll
            for (int rg = 0; rg < 4; ++rg)
              red[wg * 2048 + (i * 16 + fq * 4 + rg) * 64 + jn * 16 + fr] = acc_o[i][jn][rg];
      }
      __syncthreads();
      {
        const int f2 = t * 2;          // 1024 threads x float2 = 2048 outputs
        const int m = f2 >> 6;         // offset-channel row 0..31
        f32x2 v = {0.f, 0.f};
#pragma unroll
        for (int w = 0; w < 8; ++w) {
          f32x2 a = *(f32x2*)&red[w * 2048 + f2];
          v[0] += a[0]; v[1] += a[1];
        }
        float bo = (m < OC) ? b_off[m] : 0.f;
        v[0] += bo; v[1] += bo;
        *(f32x2*)&s_off[m * 128 + pass * 64 + (f2 & 63)] = v;
      }
      __syncthreads();
    }
  }

  // ================= main gather-GEMM loop (2-deep pipeline) =================
  f32x2 qw2[4], qwN[4];    // bilinear weights (live / staged)
  const char* ga[4];       // absolute corner addresses for the NEXT gather

  auto calc = [&](int kk, int chunk64) {
    float dy = s_off[(2 * kk) * 128 + col];
    float dx = s_off[(2 * kk + 1) * 128 + col];
    int y = 2 * hh2 + (col >> 6);
    int xx = col & 63;
    float py = (float)(kk / 3 - 1 + y) + dy;
    float pxx = (float)(kk % 3 - 1 + xx) + dx;
    float y0f = floorf(py), x0f = floorf(pxx);
    float fy = py - y0f, fx = pxx - x0f;
    int y0 = (int)y0f, x0 = (int)x0f;
    int y1 = y0 + 1, x1 = x0 + 1;
    bool vy0 = (y0 >= 0) && (y0 < HH), vy1 = (y1 >= 0) && (y1 < HH);
    bool vx0 = (x0 >= 0) && (x0 < WW), vx1 = (x1 >= 0) && (x1 < WW);
    int cy0 = min(max(y0, 0), HH - 1), cy1 = min(max(y1, 0), HH - 1);
    int cx0 = min(max(x0, 0), WW - 1), cx1 = min(max(x1, 0), WW - 1);
    float q0 = (vy0 && vx0) ? (1.f - fy) * (1.f - fx) : 0.f;
    float q1 = (vy0 && vx1) ? (1.f - fy) * fx : 0.f;
    float q2 = (vy1 && vx0) ? fy * (1.f - fx) : 0.f;
    float q3 = (vy1 && vx1) ? fy * fx : 0.f;
    const char* bp = (const char*)xtb + (((size_t)(chunk64 * 8 + oct)) << 16);
    ga[0] = bp + (cy0 * WW + cx0) * 16;  qwN[0][0] = q0; qwN[0][1] = q0;
    ga[1] = bp + (cy0 * WW + cx1) * 16;  qwN[1][0] = q1; qwN[1][1] = q1;
    ga[2] = bp + (cy1 * WW + cx0) * 16;  qwN[2][0] = q2; qwN[2][1] = q2;
    ga[3] = bp + (cy1 * WW + cx1) * 16;  qwN[3][0] = q3; qwN[3][1] = q3;
  };

  s16x8 gE[4], gO[4];      // corner data, indexed by target parity

  auto gather = [&](s16x8* g) {
#pragma unroll
    for (int k = 0; k < 4; ++k) {
      __builtin_memcpy(&g[k], ga[k], 16);
      ga[k] += 8 << 16;    // advance one 64-ch chunk (8 planes)
    }
  };

  auto combine_write = [&](int buf, const s16x8* g) {
    u32x4 vout;
#pragma unroll
    for (int jp = 0; jp < 4; ++jp) {
      f32x2 a = {0.f, 0.f};
#pragma unroll
      for (int k = 0; k < 4; ++k) {
        unsigned int pr = ((const unsigned int*)&g[k])[jp];
        f32x2 xv;
        xv[0] = __uint_as_float(pr << 16);
        xv[1] = __uint_as_float(pr & 0xffff0000u);
        a = __builtin_elementwise_fma(qw2[k], xv, a);
      }
      unsigned int packed;
      asm("v_cvt_pk_bf16_f32 %0, %1, %2" : "=v"(packed) : "v"(a[0]), "v"(a[1]));
      vout[jp] = packed;
    }
    *(u32x4*)&s_b[buf][(oct * 128 + col) * 8] = vout;
  };

  auto load_a = [&](int iter, s16x8 af[2]) {
#pragma unroll
    for (int ks = 0; ks < 2; ++ks)
      af[ks] = *(const s16x8*)&wTb[(((size_t)(iter * 2 + ks) * 4 + fq) * 256 + wv * 16 + fr) * 8];
  };

  f32x4 acc[8] = {};
  s16x8 afE[2], afO[2];

  // prologue: calc(0) -> gather t0 (gE) -> combine t0 -> gather t1 (gO);
  // qw = group0; A(0).
  {
    calc(0, 0);
#pragma unroll
    for (int k2 = 0; k2 < 4; ++k2) qw2[k2] = qwN[k2];
    gather(gE);            // target 0 (chunk 0); ga now at chunk 1
    load_a(0, afE);
    combine_write(0, gE);  // waits on the t0 loads once (prologue only)
    gather(gO);            // target 1 (chunk 1); ga now at chunk 2
  }
  asm volatile("s_waitcnt lgkmcnt(0)" ::: "memory");
  __builtin_amdgcn_s_barrier();

  // Body I: [calc if (I+2)%4==0] -> gather(I+2 -> g[I&1]) -> load_a(I+1) ->
  // MFMA(s_b[I&1]) -> combine(I+1 -> s_b[(I&1)^1], reads g[(I+1)&1], old qw)
  // -> commit qw -> barrier.
#define GBODY(I, AFC, AFN, GW, GR, CUR)                                        \
  {                                                                            \
    const int nx1 = (I) + 1, nx2 = (I) + 2;                                    \
    bool newq = false;                                                         \
    if (nx1 < 36) {                                                            \
      if (nx2 < 36) {                                                          \
        if ((nx2 & 3) == 0) { calc(nx2 >> 2, 0); newq = true; }                \
        gather(GW);                                                            \
      }                                                                        \
      load_a(nx1, AFN);                                                        \
    }                                                                          \
    __builtin_amdgcn_s_setprio(1);                                             \
    _Pragma("unroll")                                                          \
    for (int ks = 0; ks < 2; ++ks)                                             \
      _Pragma("unroll")                                                        \
      for (int jj = 0; jj < 8; ++jj) {                                         \
        s16x8 bfr = *(const s16x8*)&s_b[CUR][((ks * 4 + fq) * 128 + jj * 16 + fr) * 8]; \
        acc[jj] = __builtin_amdgcn_mfma_f32_16x16x32_bf16(                     \
            AFC[ks], bfr, acc[jj], 0, 0, 0);                                   \
      }                                                                        \
    __builtin_amdgcn_s_setprio(0);                                             \
    if (nx1 < 36) {                                                            \
      combine_write((CUR) ^ 1, GR);                                            \
      if (newq) {                                                              \
        _Pragma("unroll")                                                      \
        for (int k2 = 0; k2 < 4; ++k2) qw2[k2] = qwN[k2];                      \
      }                                                                        \
    }                                                                          \
    asm volatile("s_waitcnt lgkmcnt(0)" ::: "memory");                         \
    __builtin_amdgcn_s_barrier();                                              \
  }

  for (int m = 0; m < 18; ++m) {
    const int i0 = 2 * m;
    GBODY(i0, afE, afO, gE, gO, 0)
    GBODY(i0 + 1, afO, afE, gO, gE, 1)
  }
#undef GBODY

  // epilogue: + bias, store, fused per-channel sum/sumsq
#pragma unroll
  for (int rg = 0; rg < 4; ++rg) {
    int o = wv * 16 + fq * 4 + rg;
    float bv = bias[o];
    float* op = out + ((size_t)(b * COUT + o)) * HW + p0 + fr;
    float s = 0.f, s2 = 0.f;
#pragma unroll
    for (int j = 0; j < 8; ++j) {
      float val = acc[j][rg] + bv;
      op[j * 16] = val;
      s += val; s2 += val * val;
    }
#pragma unroll
    for (int m2 = 1; m2 < 16; m2 <<= 1) {
      s += __shfl_xor(s, m2);
      s2 += __shfl_xor(s2, m2);
    }
    if (fr == 0) {
      atomicAdd(&stats[o], s);
      atomicAdd(&stats[COUT + o], s2);
    }
  }
}

// ---------------- Kernel D: normalize + ReLU in-place ----------------
__global__ __launch_bounds__(256) void bn_kernel(
    float* __restrict__ out, const float* __restrict__ stats,
    const float* __restrict__ gamma, const float* __restrict__ beta) {
  int i4 = (blockIdx.x * 256 + threadIdx.x) * 4;
  int o = (i4 >> 12) & (COUT - 1);
  const float inv_n = 1.f / (float)(BN_ * HW);
  float mean = stats[o] * inv_n;
  float var = stats[COUT + o] * inv_n - mean * mean;
  float sc = gamma[o] * rsqrtf(var + EPS);
  float sh = beta[o] - mean * sc;
  float4 v = *(float4*)(out + i4);
  v.x = fmaxf(fmaf(v.x, sc, sh), 0.f);
  v.y = fmaxf(fmaf(v.y, sc, sh), 0.f);
  v.z = fmaxf(fmaf(v.z, sc, sh), 0.f);
  v.w = fmaxf(fmaf(v.w, sc, sh), 0.f);
  *(float4*)(out + i4) = v;
}

extern "C" void kernel_launch(void* const* d_in, const int* in_sizes, int n_in,
                              void* d_out, int out_size, void* d_ws, size_t ws_size,
                              hipStream_t stream) {
  const float* x     = (const float*)d_in[0];
  const float* w_off = (const float*)d_in[1];
  const float* b_off = (const float*)d_in[2];
  const float* w     = (const float*)d_in[3];
  const float* bias  = (const float*)d_in[4];
  const float* gamma = (const float*)d_in[5];
  const float* beta  = (const float*)d_in[6];
  float* out = (float*)d_out;
  float* ws = (float*)d_ws;
  unsigned short* wTb = (unsigned short*)(ws + WTB_WS);
  unsigned short* wob = (unsigned short*)(ws + WOB_WS);
  float* stats = ws + ST_WS;
  unsigned short* xt = (unsigned short*)(ws + XT_WS);

  xpose_kernel<<<dim3(64, 4, 8), 256, 0, stream>>>(x, xt);
  prep_kernel<<<72, 256, 0, stream>>>(w_off, w, wob, wTb, stats);
  gemm_kernel<<<256, 1024, 0, stream>>>(xt, wTb, wob, b_off, bias, out, stats);
  bn_kernel<<<NTOT / 1024, 256, 0, stream>>>(out, stats, gamma, beta);
}

// Round 12
// 196.414 us; speedup vs baseline: 1.1914x; 1.1914x over previous
//
#include <hip/hip_runtime.h>
#include <math.h>

#define BN_ 8
#define CIN 256
#define COUT 256
#define HH 64
#define WW 64
#define HW 4096
#define KK 9
#define OC 18
#define EPS 1e-5f
#define NTOT (BN_ * COUT * HW)

// ws layout (float units):
//   wTb:    bf16 [72][4][256][8] shorts = 294912 floats (main GEMM A image)
//   wob:    bf16 [72][4][32][8] shorts  = 36864 floats  (offset-conv A image)
//   stats:  [2][COUT]                   = 512 floats
//   xt:     bf16 [B][32][HW][8] shorts  = 4194304 floats (g8-planar x)
#define WTB_WS 589824
#define WOB_WS 884736
#define ST_WS  921600
#define XT_WS  922112

typedef float f32x4 __attribute__((ext_vector_type(4)));
typedef float f32x2 __attribute__((ext_vector_type(2)));
typedef short s16x8 __attribute__((ext_vector_type(8)));
typedef unsigned int u32x4 __attribute__((ext_vector_type(4)));

__device__ __forceinline__ unsigned short f2bf(float f) {
  unsigned int u = __float_as_uint(f);
  unsigned int r = (u + 0x7fffu + ((u >> 16) & 1u)) >> 16;  // RNE
  return (unsigned short)r;
}
__device__ __forceinline__ float bf2f(short s) {
  return __uint_as_float(((unsigned int)(unsigned short)s) << 16);
}

// ---------------- Kernel TP: transpose x -> xt AND pack weights (merged) ----------------
// 1D grid 2048 = (b:8)(c-tile:4)(p-tile:64), block 256. Blocks 0..71 also do
// the prep packing (w_off -> wob, w -> wTb, stats zero) — hides the tiny prep
// dispatch under the memory-bound transpose and removes one launch boundary.
__global__ __launch_bounds__(256) void xpose_prep_kernel(
    const float* __restrict__ x, const float* __restrict__ w_off,
    const float* __restrict__ w, unsigned short* __restrict__ xt,
    unsigned short* __restrict__ wob, unsigned short* __restrict__ wTb,
    float* __restrict__ stats) {
  __shared__ float s[64][65];
  const int t = threadIdx.x;
  const int bx = blockIdx.x;
  const int p0 = (bx & 63) * 64;
  const int c0 = ((bx >> 6) & 3) * 64;
  const int b  = bx >> 8;
  const float* xb = x + ((size_t)b * CIN + c0) * HW + p0;
#pragma unroll
  for (int pass = 0; pass < 4; ++pass) {
    int cr = pass * 16 + (t >> 4);
    int ps = (t & 15) * 4;
    float4 v = *(const float4*)(xb + (size_t)cr * HW + ps);
    s[ps + 0][cr] = v.x; s[ps + 1][cr] = v.y; s[ps + 2][cr] = v.z; s[ps + 3][cr] = v.w;
  }
  __syncthreads();
  unsigned short* xo = xt + (size_t)b * 32 * HW * 8;
#pragma unroll
  for (int r = 0; r < 2; ++r) {
    int flat = r * 256 + t;
    int pr = flat >> 3, sub = flat & 7;
    int g8 = (c0 >> 3) + sub;
    s16x8 v;
#pragma unroll
    for (int j = 0; j < 8; ++j) v[j] = (short)f2bf(s[pr][sub * 8 + j]);
    *(s16x8*)(xo + ((size_t)g8 * HW + p0 + pr) * 8) = v;
  }

  // ---- prep part (blocks 0..71) ----
  if (bx < 72) {
    const int kb = bx;
    const int kk = kb >> 3;
    const int cc0 = (kb & 7) << 5;
    if (kb == 71) { stats[t] = 0.f; stats[256 + t] = 0.f; }
#pragma unroll
    for (int r = 0; r < 4; ++r) {
      int e = r * 256 + t;            // g*256 + m*8 + j
      int g = e >> 8, m = (e >> 3) & 31, j = e & 7;
      int c = cc0 + g * 8 + j;
      unsigned short v = 0;
      if (m < OC) v = f2bf(w_off[((size_t)m * CIN + c) * 9 + kk]);
      wob[(size_t)kb * 1024 + e] = v;
    }
#pragma unroll
    for (int g = 0; g < 4; ++g)
#pragma unroll
      for (int j = 0; j < 8; ++j) {
        int c = cc0 + g * 8 + j;
        wTb[(((size_t)kb * 4 + g) * 256 + t) * 8 + j] =
            f2bf(w[((size_t)t * CIN + c) * 9 + kk]);
      }
  }
}

// ---------------- Kernel B: fused offset-conv + gather MFMA GEMM, N=128 ----------------
// EXACT round-10 body (best measured: 100.2us, VGPR 64, no spill). The R11
// 2-deep pipeline variant added ~32 live VGPRs and the allocator spilled
// (FETCH +37MB / WRITE +33MB of scratch traffic, -35% perf) — reverted.
__global__ __launch_bounds__(1024, 4) void gemm_kernel(
    const unsigned short* __restrict__ xt, const unsigned short* __restrict__ wTb,
    const unsigned short* __restrict__ wob, const float* __restrict__ b_off,
    const float* __restrict__ bias, float* __restrict__ out,
    float* __restrict__ stats) {
  __shared__ __align__(16) char lds[81920];   // 64KB sb/red (s_b aliases) + 16KB s_off
  const int t = threadIdx.x;
  const int lane = t & 63;
  const int wv = t >> 6;               // 0..15
  const int b = blockIdx.x & 7;
  const int hh2 = blockIdx.x >> 3;     // double-row tile: rows 2*hh2, 2*hh2+1
  const int p0 = hh2 * 128;
  const int col = t & 127;             // gather pixel within 128-px tile
  const int oct = t >> 7;              // channel octet (8ch) within 64-chunk
  const int fr = lane & 15, fq = lane >> 4;
  const unsigned short* xtb = xt + (size_t)b * 32 * HW * 8;
  float* s_off = (float*)(lds + 65536);          // [32][128] f32 (rows 0..17 used)
  unsigned short (*s_b)[8192] = (unsigned short(*)[8192])lds;  // 2 x 16KB, aliases red

  // ================= offset-conv prologue =================
  {
    const int wg = wv & 7;             // ki group: ki = wg*9 + s
    const int half = wv >> 3;          // pixel half == row within tile
    const int yrow = 2 * hh2 + half;
    unsigned short* sb = (unsigned short*)lds + wv * 2048;  // wave-private 4KB
    f32x4 acc_o[2][4] = {};

    auto fetch = [&](int s, s16x8* V, s16x8* AF) {
      const int ki = wg * 9 + s;
      const int kk = ki >> 3, cc0g = (ki & 7) << 2;
      const int ky = kk / 3 - 1, kx = kk % 3 - 1;
      const int y = yrow + ky;
      const int xcol = lane + kx;
      const bool ok = (y >= 0) && (y < HH) && (xcol >= 0) && (xcol < WW);
      const int pix = y * WW + xcol;
#pragma unroll
      for (int g = 0; g < 4; ++g) {
        s16x8 v = {0, 0, 0, 0, 0, 0, 0, 0};
        if (ok)
          __builtin_memcpy(&v, (const char*)xtb + (((size_t)(cc0g + g)) << 16) + (size_t)pix * 16, 16);
        V[g] = v;
      }
      const unsigned short* ap = wob + (size_t)ki * 1024;
#pragma unroll
      for (int i = 0; i < 2; ++i)
        AF[i] = *(const s16x8*)&ap[(fq * 32 + i * 16 + fr) * 8];
    };

    s16x8 VE[4], VO[4], afE2[2], afO2[2];
    fetch(0, VE, afE2);

#define OBODY(S, VC, VN, AFC, AFN)                                             \
    {                                                                          \
      _Pragma("unroll")                                                        \
      for (int g = 0; g < 4; ++g)                                              \
        *(s16x8*)&sb[(g * 64 + lane) * 8] = VC[g];                             \
      if ((S) + 1 < 9) fetch((S) + 1, VN, AFN);                                \
      s16x8 bf[4];                                                             \
      _Pragma("unroll")                                                        \
      for (int jn = 0; jn < 4; ++jn)                                           \
        bf[jn] = *(const s16x8*)&sb[(fq * 64 + jn * 16 + fr) * 8];             \
      _Pragma("unroll")                                                        \
      for (int i = 0; i < 2; ++i)                                              \
        _Pragma("unroll")                                                      \
        for (int jn = 0; jn < 4; ++jn)                                         \
          acc_o[i][jn] = __builtin_amdgcn_mfma_f32_16x16x32_bf16(              \
              AFC[i], bf[jn], acc_o[i][jn], 0, 0, 0);                          \
    }

    for (int sp = 0; sp < 4; ++sp) {
      OBODY(2 * sp, VE, VO, afE2, afO2)
      OBODY(2 * sp + 1, VO, VE, afO2, afE2)
    }
    OBODY(8, VE, VO, afE2, afO2)
#undef OBODY

    __syncthreads();                  // sb dead; red region takes over
    float* red = (float*)lds;
    // two passes: half h's 8 wave-partials (64KB) -> reduce -> s_off cols
#pragma unroll
    for (int pass = 0; pass < 2; ++pass) {
      if (half == pass) {
#pragma unroll
        for (int i = 0; i < 2; ++i)
#pragma unroll
          for (int jn = 0; jn < 4; ++jn)
#pragma unroll
            for (int rg = 0; rg < 4; ++rg)
              red[wg * 2048 + (i * 16 + fq * 4 + rg) * 64 + jn * 16 + fr] = acc_o[i][jn][rg];
      }
      __syncthreads();
      {
        const int f2 = t * 2;          // 1024 threads x float2 = 2048 outputs
        const int m = f2 >> 6;         // offset-channel row 0..31
        f32x2 v = {0.f, 0.f};
#pragma unroll
        for (int w = 0; w < 8; ++w) {
          f32x2 a = *(f32x2*)&red[w * 2048 + f2];
          v[0] += a[0]; v[1] += a[1];
        }
        float bo = (m < OC) ? b_off[m] : 0.f;
        v[0] += bo; v[1] += bo;
        *(f32x2*)&s_off[m * 128 + pass * 64 + (f2 & 63)] = v;
      }
      __syncthreads();
    }
  }

  // ================= main gather-GEMM loop (R10 body) =================
  int cofs[4];       // corner byte offsets within a g8 plane: (cy*WW+cx)*16
  f32x2 qw2[4];      // bilinear weights, broadcast into both f32 lanes

  auto calc = [&](int kk) {
    float dy = s_off[(2 * kk) * 128 + col];
    float dx = s_off[(2 * kk + 1) * 128 + col];
    int y = 2 * hh2 + (col >> 6);
    int xx = col & 63;
    float py = (float)(kk / 3 - 1 + y) + dy;
    float pxx = (float)(kk % 3 - 1 + xx) + dx;
    float y0f = floorf(py), x0f = floorf(pxx);
    float fy = py - y0f, fx = pxx - x0f;
    int y0 = (int)y0f, x0 = (int)x0f;
    int y1 = y0 + 1, x1 = x0 + 1;
    bool vy0 = (y0 >= 0) && (y0 < HH), vy1 = (y1 >= 0) && (y1 < HH);
    bool vx0 = (x0 >= 0) && (x0 < WW), vx1 = (x1 >= 0) && (x1 < WW);
    int cy0 = min(max(y0, 0), HH - 1), cy1 = min(max(y1, 0), HH - 1);
    int cx0 = min(max(x0, 0), WW - 1), cx1 = min(max(x1, 0), WW - 1);
    float q0 = (vy0 && vx0) ? (1.f - fy) * (1.f - fx) : 0.f;
    float q1 = (vy0 && vx1) ? (1.f - fy) * fx : 0.f;
    float q2 = (vy1 && vx0) ? fy * (1.f - fx) : 0.f;
    float q3 = (vy1 && vx1) ? fy * fx : 0.f;
    cofs[0] = (cy0 * WW + cx0) * 16;  qw2[0][0] = q0; qw2[0][1] = q0;
    cofs[1] = (cy0 * WW + cx1) * 16;  qw2[1][0] = q1; qw2[1][1] = q1;
    cofs[2] = (cy1 * WW + cx0) * 16;  qw2[2][0] = q2; qw2[2][1] = q2;
    cofs[3] = (cy1 * WW + cx1) * 16;  qw2[3][0] = q3; qw2[3][1] = q3;
  };

  s16x8 g[4];        // corner data for the in-flight target iter

  auto gather = [&](int chunk64) {
    const char* bp = (const char*)xtb + (((size_t)(chunk64 * 8 + oct)) << 16);
#pragma unroll
    for (int k = 0; k < 4; ++k)
      __builtin_memcpy(&g[k], bp + cofs[k], 16);
  };

  auto combine_write = [&](int buf) {
    u32x4 vout;
#pragma unroll
    for (int jp = 0; jp < 4; ++jp) {
      f32x2 a = {0.f, 0.f};
#pragma unroll
      for (int k = 0; k < 4; ++k) {
        unsigned int pr = ((const unsigned int*)&g[k])[jp];
        f32x2 xv;
        xv[0] = __uint_as_float(pr << 16);
        xv[1] = __uint_as_float(pr & 0xffff0000u);
        a = __builtin_elementwise_fma(qw2[k], xv, a);
      }
      unsigned int packed;
      asm("v_cvt_pk_bf16_f32 %0, %1, %2" : "=v"(packed) : "v"(a[0]), "v"(a[1]));
      vout[jp] = packed;
    }
    *(u32x4*)&s_b[buf][(oct * 128 + col) * 8] = vout;
  };

  auto load_a = [&](int iter, s16x8 af[2]) {
#pragma unroll
    for (int ks = 0; ks < 2; ++ks)
      af[ks] = *(const s16x8*)&wTb[(((size_t)(iter * 2 + ks) * 4 + fq) * 256 + wv * 16 + fr) * 8];
  };

  f32x4 acc[8] = {};
  s16x8 afE[2], afO[2];

  {
    calc(0);
    gather(0);
    load_a(0, afE);
    combine_write(0);
  }
  asm volatile("s_waitcnt lgkmcnt(0)" ::: "memory");
  __builtin_amdgcn_s_barrier();

#define GBODY(I, AFC, AFN, CUR)                                                \
  {                                                                            \
    const int nx1 = (I) + 1;                                                   \
    if (nx1 < 36) {                                                            \
      if ((nx1 & 3) == 0) calc(nx1 >> 2);                                      \
      gather(nx1 & 3);                                                         \
      load_a(nx1, AFN);                                                        \
    }                                                                          \
    __builtin_amdgcn_s_setprio(1);                                             \
    _Pragma("unroll")                                                          \
    for (int ks = 0; ks < 2; ++ks)                                             \
      _Pragma("unroll")                                                        \
      for (int jj = 0; jj < 8; ++jj) {                                         \
        s16x8 bfr = *(const s16x8*)&s_b[CUR][((ks * 4 + fq) * 128 + jj * 16 + fr) * 8]; \
        acc[jj] = __builtin_amdgcn_mfma_f32_16x16x32_bf16(                     \
            AFC[ks], bfr, acc[jj], 0, 0, 0);                                   \
      }                                                                        \
    __builtin_amdgcn_s_setprio(0);                                             \
    if (nx1 < 36) {                                                            \
      combine_write((CUR) ^ 1);                                                \
      asm volatile("s_waitcnt lgkmcnt(0)" ::: "memory");                       \
      __builtin_amdgcn_s_barrier();                                            \
    }                                                                          \
  }

  for (int m = 0; m < 18; ++m) {
    const int i0 = 2 * m;
    GBODY(i0, afE, afO, 0)
    GBODY(i0 + 1, afO, afE, 1)
  }
#undef GBODY

  // epilogue: + bias, store, fused per-channel sum/sumsq
#pragma unroll
  for (int rg = 0; rg < 4; ++rg) {
    int o = wv * 16 + fq * 4 + rg;
    float bv = bias[o];
    float* op = out + ((size_t)(b * COUT + o)) * HW + p0 + fr;
    float s = 0.f, s2 = 0.f;
#pragma unroll
    for (int j = 0; j < 8; ++j) {
      float val = acc[j][rg] + bv;
      op[j * 16] = val;
      s += val; s2 += val * val;
    }
#pragma unroll
    for (int m2 = 1; m2 < 16; m2 <<= 1) {
      s += __shfl_xor(s, m2);
      s2 += __shfl_xor(s2, m2);
    }
    if (fr == 0) {
      atomicAdd(&stats[o], s);
      atomicAdd(&stats[COUT + o], s2);
    }
  }
}

// ---------------- Kernel D: normalize + ReLU in-place ----------------
__global__ __launch_bounds__(256) void bn_kernel(
    float* __restrict__ out, const float* __restrict__ stats,
    const float* __restrict__ gamma, const float* __restrict__ beta) {
  int i4 = (blockIdx.x * 256 + threadIdx.x) * 4;
  int o = (i4 >> 12) & (COUT - 1);
  const float inv_n = 1.f / (float)(BN_ * HW);
  float mean = stats[o] * inv_n;
  float var = stats[COUT + o] * inv_n - mean * mean;
  float sc = gamma[o] * rsqrtf(var + EPS);
  float sh = beta[o] - mean * sc;
  float4 v = *(float4*)(out + i4);
  v.x = fmaxf(fmaf(v.x, sc, sh), 0.f);
  v.y = fmaxf(fmaf(v.y, sc, sh), 0.f);
  v.z = fmaxf(fmaf(v.z, sc, sh), 0.f);
  v.w = fmaxf(fmaf(v.w, sc, sh), 0.f);
  *(float4*)(out + i4) = v;
}

extern "C" void kernel_launch(void* const* d_in, const int* in_sizes, int n_in,
                              void* d_out, int out_size, void* d_ws, size_t ws_size,
                              hipStream_t stream) {
  const float* x     = (const float*)d_in[0];
  const float* w_off = (const float*)d_in[1];
  const float* b_off = (const float*)d_in[2];
  const float* w     = (const float*)d_in[3];
  const float* bias  = (const float*)d_in[4];
  const float* gamma = (const float*)d_in[5];
  const float* beta  = (const float*)d_in[6];
  float* out = (float*)d_out;
  float* ws = (float*)d_ws;
  unsigned short* wTb = (unsigned short*)(ws + WTB_WS);
  unsigned short* wob = (unsigned short*)(ws + WOB_WS);
  float* stats = ws + ST_WS;
  unsigned short* xt = (unsigned short*)(ws + XT_WS);

  xpose_prep_kernel<<<2048, 256, 0, stream>>>(x, w_off, w, xt, wob, wTb, stats);
  gemm_kernel<<<256, 1024, 0, stream>>>(xt, wTb, wob, b_off, bias, out, stats);
  bn_kernel<<<NTOT / 1024, 256, 0, stream>>>(out, stats, gamma, beta);
}